// Round 7
// baseline (487.538 us; speedup 1.0000x reference)
//
#include <hip/hip_runtime.h>
#include <hip/hip_bf16.h>
#include <math.h>

using bf16 = __hip_bfloat16;
typedef __bf16 bf16x8 __attribute__((ext_vector_type(8)));
typedef float f32x4 __attribute__((ext_vector_type(4)));

#define SEQ 2048
#define DIM 1024
#define NH 16
#define HDIM 64
#define BATCH 2

// async global->LDS, 16B per lane; LDS dest = base + lane*16 (wave-uniform base)
__device__ __forceinline__ void load_lds16(const bf16* g, bf16* l) {
  __builtin_amdgcn_global_load_lds((__attribute__((address_space(1))) void*)g,
                                   (__attribute__((address_space(3))) void*)l, 16, 0, 0);
}

// ---------------- convert+transpose: in f32 [R][C] -> out bf16 [C][R] ----------------
__global__ __launch_bounds__(256) void transpose_k(const float* __restrict__ in,
                                                   bf16* __restrict__ out, int R, int C) {
  __shared__ float tile[32][33];
  int c0 = blockIdx.x * 32, r0 = blockIdx.y * 32;
  int tx = threadIdx.x, ty = threadIdx.y;  // (32,8)
#pragma unroll
  for (int j = 0; j < 4; ++j)
    tile[ty + 8 * j][tx] = in[(size_t)(r0 + ty + 8 * j) * C + c0 + tx];
  __syncthreads();
#pragma unroll
  for (int j = 0; j < 4; ++j)
    out[(size_t)(c0 + ty + 8 * j) * R + r0 + tx] = __float2bfloat16(tile[tx][ty + 8 * j]);
}

// ---------------- layernorm (torch-style: unbiased std, /(std+eps)); f32 in, bf16 out ----
// Optional fused init: initout[row][c] = x[row][c] + addb[c]  (pre-inits a split-K GEMM dest)
__global__ __launch_bounds__(256) void ln_k(const float* __restrict__ x,
                                            const float* __restrict__ w,
                                            const float* __restrict__ bb,
                                            bf16* __restrict__ out,
                                            const float* __restrict__ addb,
                                            float* __restrict__ initout) {
  int row = blockIdx.x, tid = threadIdx.x;
  int wid = tid >> 6, lane = tid & 63;
  const float* xr = x + (size_t)row * DIM;
  float4 vv = *(const float4*)&xr[tid * 4];  // 16B/lane coalesced
  if (initout) {
    float4 ab = *(const float4*)&addb[tid * 4];
    float4 iv;
    iv.x = vv.x + ab.x; iv.y = vv.y + ab.y; iv.z = vv.z + ab.z; iv.w = vv.w + ab.w;
    *(float4*)&initout[(size_t)row * DIM + tid * 4] = iv;
  }
  float v[4] = {vv.x, vv.y, vv.z, vv.w};
  float s = v[0] + v[1] + v[2] + v[3];
#pragma unroll
  for (int m = 1; m < 64; m <<= 1) s += __shfl_xor(s, m, 64);
  __shared__ float red[8];
  if (lane == 0) red[wid] = s;
  __syncthreads();
  float mean = (red[0] + red[1] + red[2] + red[3]) * (1.f / DIM);
  float q = 0.f;
#pragma unroll
  for (int j = 0; j < 4; ++j) {
    v[j] -= mean;
    q += v[j] * v[j];
  }
#pragma unroll
  for (int m = 1; m < 64; m <<= 1) q += __shfl_xor(q, m, 64);
  if (lane == 0) red[4 + wid] = q;
  __syncthreads();
  float ssq = red[4] + red[5] + red[6] + red[7];
  float sd = sqrtf(ssq / (float)(DIM - 1));
  float inv = 1.f / (sd + 1e-5f);
  float4 wv = *(const float4*)&w[tid * 4];
  float4 bv4 = *(const float4*)&bb[tid * 4];
  float wl[4] = {wv.x, wv.y, wv.z, wv.w};
  float bl[4] = {bv4.x, bv4.y, bv4.z, bv4.w};
  unsigned short pk[4];
#pragma unroll
  for (int j = 0; j < 4; ++j)
    pk[j] = __bfloat16_as_ushort(__float2bfloat16(wl[j] * (v[j] * inv) + bl[j]));
  *(uint2*)&out[(size_t)row * DIM + tid * 4] = *(uint2*)pk;
}

// ============ 256x256-tile 8-wave phased GEMM: C[M,N] = A[M,Ks] @ Bt[N,Ks]^T ============
// BK=64 split into two col-halves (ks). 4 phases per K-tile, 2 barriers/phase, counted
// vmcnt(8) only at ph1/ph3. Kstride = row stride of A/Bt; klen = this block's reduction
// length; blockIdx.z selects the K-split (kOff = z*klen). Modes:
//   0: split qkv (q,k -> [B,H,S,HD]; v -> [B,H,HD,S]) + bias
//   2: o0 = gelu(acc + bias)
//   4: split-K partial: atomicAdd(fdst[row*N+col], acc)  (dest pre-initialized, no bias)
__global__ __launch_bounds__(512) void gemm256_k(
    const bf16* __restrict__ A, const bf16* __restrict__ Bt, const float* __restrict__ bias,
    int N, int Kstride, int klen, int mode, bf16* __restrict__ o0, bf16* __restrict__ o1,
    bf16* __restrict__ o2, float* __restrict__ fdst) {
  __shared__ bf16 LDSb[65536];  // [buf][A ks0|ks1 16KB each][B ks0|ks1] = 128 KB
  int tid = threadIdx.x;
  int wid = tid >> 6, lane = tid & 63, quad = lane >> 4, l15 = lane & 15;
  int wm = wid >> 2, wn = wid & 3;  // 2M x 4N wave grid; per-wave out 128x64
  int m0 = blockIdx.y * 256, n0 = blockIdx.x * 256;
  int grow = lane >> 2;                       // row within 16-row chunk
  int gslot = (lane & 3) ^ ((lane >> 3) & 3); // pre-swizzled global 16B col-slot
  const int nt = klen >> 6;
  const int kOff = blockIdx.z * klen;

  // bias preload BEFORE any staging: oldest vmem, retires first, never perturbs vmcnt counts
  float bv[4] = {0.f, 0.f, 0.f, 0.f};
  if (bias) {
#pragma unroll
    for (int nf = 0; nf < 4; ++nf) bv[nf] = bias[n0 + wn * 64 + nf * 16 + l15];
  }

  auto stageA = [&](int tile, int ks) {
    int bd = tile & 1;
#pragma unroll
    for (int it = 0; it < 2; ++it) {
      int c = wid * 2 + it;  // 16 chunks of 16 rows x 32 cols (1KB) per col-half
      load_lds16(
          A + (size_t)(m0 + c * 16 + grow) * Kstride + kOff + tile * 64 + ks * 32 + gslot * 8,
          &LDSb[bd * 32768 + ks * 8192 + c * 512]);
    }
  };
  auto stageB = [&](int tile, int ks) {
    int bd = tile & 1;
#pragma unroll
    for (int it = 0; it < 2; ++it) {
      int c = wid * 2 + it;
      load_lds16(
          Bt + (size_t)(n0 + c * 16 + grow) * Kstride + kOff + tile * 64 + ks * 32 + gslot * 8,
          &LDSb[bd * 32768 + 16384 + ks * 8192 + c * 512]);
    }
  };

  f32x4 acc[8][4] = {};

  // prologue: tile0 both halves + tile1 ks0; wait oldest batch (tile0 ks0) landed
  stageA(0, 0); stageB(0, 0);
  stageA(0, 1); stageB(0, 1);
  stageA(1, 0); stageB(1, 0);
  asm volatile("s_waitcnt vmcnt(8)" ::: "memory");
  __builtin_amdgcn_sched_barrier(0);
  __builtin_amdgcn_s_barrier();
  __builtin_amdgcn_sched_barrier(0);

#define PHASE(BD, KS, MH, STAGE_STMT, WAIT_STMT)                                             \
  {                                                                                          \
    bf16x8 af[4], bq[4];                                                                     \
    _Pragma("unroll") for (int j = 0; j < 4; ++j) {                                          \
      int r = wm * 128 + (MH) * 64 + j * 16 + l15;                                           \
      af[j] = *(const bf16x8*)&LDSb[(BD) * 32768 + (KS) * 8192 + (r >> 4) * 512 +            \
                                    (r & 15) * 32 + ((quad ^ ((r >> 1) & 3)) << 3)];         \
    }                                                                                        \
    _Pragma("unroll") for (int n = 0; n < 4; ++n) {                                          \
      int r = wn * 64 + n * 16 + l15;                                                        \
      bq[n] = *(const bf16x8*)&LDSb[(BD) * 32768 + 16384 + (KS) * 8192 + (r >> 4) * 512 +    \
                                    (r & 15) * 32 + ((quad ^ ((r >> 1) & 3)) << 3)];         \
    }                                                                                        \
    STAGE_STMT;                                                                              \
    __builtin_amdgcn_sched_barrier(0);                                                       \
    __builtin_amdgcn_s_barrier();                                                            \
    __builtin_amdgcn_sched_barrier(0);                                                       \
    __builtin_amdgcn_s_setprio(1);                                                           \
    _Pragma("unroll") for (int j = 0; j < 4; ++j)                                            \
        _Pragma("unroll") for (int n = 0; n < 4; ++n)                                        \
            acc[(MH) * 4 + j][n] = __builtin_amdgcn_mfma_f32_16x16x32_bf16(                  \
                af[j], bq[n], acc[(MH) * 4 + j][n], 0, 0, 0);                                \
    __builtin_amdgcn_s_setprio(0);                                                           \
    WAIT_STMT;                                                                               \
    __builtin_amdgcn_sched_barrier(0);                                                       \
    __builtin_amdgcn_s_barrier();                                                            \
    __builtin_amdgcn_sched_barrier(0);                                                       \
  }

  for (int t = 0; t < nt; ++t) {
    int bd = t & 1;
    PHASE(bd, 0, 0, { if (t + 1 < nt) stageA(t + 1, 1); }, {});
    PHASE(bd, 0, 1, { if (t + 1 < nt) stageB(t + 1, 1); }, {
      if (t + 1 < nt) asm volatile("s_waitcnt vmcnt(8)" ::: "memory");
      else            asm volatile("s_waitcnt vmcnt(0)" ::: "memory");
    });
    PHASE(bd, 1, 0, { if (t + 2 < nt) stageA(t + 2, 0); }, {});
    PHASE(bd, 1, 1, { if (t + 2 < nt) stageB(t + 2, 0); }, {
      if (t + 2 < nt)      asm volatile("s_waitcnt vmcnt(8)" ::: "memory");
      else if (t + 1 < nt) asm volatile("s_waitcnt vmcnt(4)" ::: "memory");
    });
  }
#undef PHASE

#pragma unroll
  for (int mf = 0; mf < 8; ++mf) {
#pragma unroll
    for (int nf = 0; nf < 4; ++nf) {
      int col = n0 + wn * 64 + nf * 16 + l15;
      int row_base = m0 + wm * 128 + mf * 16 + quad * 4;
      if (mode == 0) {
        int which = col >> 10, d = col & 1023, hh = d >> 6, dd = d & 63;
        int b = row_base >> 11, s2 = row_base & 2047;
        if (which == 2) {
          unsigned short pk[4];
#pragma unroll
          for (int r = 0; r < 4; ++r)
            pk[r] = __bfloat16_as_ushort(__float2bfloat16(acc[mf][nf][r] + bv[nf]));
          *(uint2*)&o2[(((size_t)b * NH + hh) * HDIM + dd) * SEQ + s2] = *(uint2*)pk;
        } else {
          bf16* dst = which == 0 ? o0 : o1;
#pragma unroll
          for (int r = 0; r < 4; ++r)
            dst[(((size_t)b * NH + hh) * SEQ + s2 + r) * HDIM + dd] =
                __float2bfloat16(acc[mf][nf][r] + bv[nf]);
        }
      } else if (mode == 2) {
#pragma unroll
        for (int r = 0; r < 4; ++r) {
          float t2 = acc[mf][nf][r] + bv[nf];
          // gelu via sigmoid: 0.5t(1+tanh(u)) = t*sigmoid(2u)
          float u = 0.7978845608028654f * (t2 + 0.044715f * t2 * t2 * t2);
          float g = t2 / (1.f + __expf(-2.f * u));
          o0[(size_t)(row_base + r) * N + col] = __float2bfloat16(g);
        }
      } else {  // mode 4: split-K partial, dest pre-initialized with residual+bias
#pragma unroll
        for (int r = 0; r < 4; ++r)
          atomicAdd(&fdst[(size_t)(row_base + r) * N + col], acc[mf][nf][r]);
      }
    }
  }
}

// ---------------- V suffix-sum: suf[bh][d][q] = sum_{k>q} Vt[bh][d][k] (fp32) ----------------
__global__ __launch_bounds__(256) void sufv_k(const bf16* __restrict__ vt,
                                              float* __restrict__ suf) {
  int row = blockIdx.x;  // (b*NH+h)*HDIM + d
  const bf16* src = vt + (size_t)row * SEQ;
  float* dst = suf + (size_t)row * SEQ;
  int tid = threadIdx.x;
  float v[8];
  float s = 0.f;
#pragma unroll
  for (int j = 0; j < 8; ++j) {
    v[j] = __bfloat162float(src[tid * 8 + j]);
    s += v[j];
  }
  __shared__ float sc[256];
  sc[tid] = s;
  __syncthreads();
  for (int off = 1; off < 256; off <<= 1) {
    float add = (tid + off < 256) ? sc[tid + off] : 0.f;
    __syncthreads();
    sc[tid] += add;
    __syncthreads();
  }
  float run = (tid < 255) ? sc[tid + 1] : 0.f;  // exclusive suffix carry
#pragma unroll
  for (int j = 7; j >= 0; --j) {
    dst[tid * 8 + j] = run;
    run += v[j];
  }
}

// Ps swizzle: chunk ^ ((row&7) ^ (((row>>3)&1)<<1)) — bijective per row
__device__ __forceinline__ int pswz(int row) { return (row & 7) ^ (((row >> 3) & 1) << 1); }

// ---------------- attention: triangular, fixed-ref softmax, dbuf + swizzled ----------------
// UNIFORM-WORK blocks: two tasks/block (qt=31-y then qt=y, same head) -> 33 tile-units each.
// Epilogue ALSO pre-initializes wo's split-K destination: x2 = x + bo (free init under
// attn's BW headroom; stream order guarantees init-before-atomics).
__global__ __launch_bounds__(256) void attn_k(const bf16* __restrict__ q,
                                              const bf16* __restrict__ k,
                                              const bf16* __restrict__ v,
                                              const int* __restrict__ rel,
                                              const float* __restrict__ rel_emb,
                                              const float* __restrict__ suf,
                                              bf16* __restrict__ out,
                                              const float* __restrict__ xin,
                                              const float* __restrict__ bo_,
                                              float* __restrict__ x2f) {
  int h = blockIdx.x;
  int y = blockIdx.y;  // 0..15
  int b = blockIdx.z;
  int tid = threadIdx.x;
  int wid = tid >> 6, lane = tid & 63, quad = lane >> 4, l15 = lane & 15;

  __shared__ __align__(16) char SM[40960];
  bf16* Kb = (bf16*)SM;                        // [2][64][64] swizzled chunks
  bf16* Vb = (bf16*)(SM + 16384);              // [2][64][64] swizzled ([d][key])
  bf16* Ps = (bf16*)(SM + 32768);              // [64][64] swizzled
  float(*SufLds)[68] = (float(*)[68])SM;       // epilogue alias over K/V dbuf (17408 B)

  const size_t bh = (size_t)b * NH + h;
  const bf16* kb0 = k + bh * SEQ * HDIM;
  const bf16* vt0 = v + bh * (size_t)HDIM * SEQ;

  float rv = 0.125f * rel_emb[lane * NH + h];

  int rsub = lane >> 3;
  int c8 = (lane & 7) ^ rsub;  // pre-swizzled source chunk -> linear LDS dest

  const int prow_w = wid * 16 + quad * 4;
  const int prow_r = wid * 16 + l15;
  const int psw_r = pswz(prow_r);

  // bo values for this lane's 4 output columns
  float bov[4];
#pragma unroll
  for (int nt = 0; nt < 4; ++nt) bov[nt] = bo_[h * HDIM + nt * 16 + l15];

  for (int sub = 0; sub < 2; ++sub) {
    int qt = (sub == 0) ? (31 - y) : y;  // heavy task first; pair sums to uniform work

    const bf16* qb = q + (bh * SEQ + (size_t)qt * 64) * HDIM;
    bf16x8 aq[2];
#pragma unroll
    for (int ks = 0; ks < 2; ++ks)
      aq[ks] = *(const bf16x8*)(qb + (size_t)(wid * 16 + l15) * HDIM + ks * 32 + quad * 8);

    // fence: previous task's epilogue reads of SufLds (aliasing K/V dbuf) must complete
    __syncthreads();

#pragma unroll
    for (int it = 0; it < 2; ++it) {
      int c = wid * 2 + it;
      int row = c * 8 + rsub;
      load_lds16(kb0 + (size_t)row * HDIM + c8 * 8, &Kb[c * 512]);
      load_lds16(vt0 + (size_t)row * SEQ + c8 * 8, &Vb[c * 512]);
    }

    const int* relq = rel + (size_t)b * SEQ * SEQ + (size_t)qt * 64 * SEQ;
    const int* rp[4];
#pragma unroll
    for (int r = 0; r < 4; ++r) rp[r] = relq + (size_t)(wid * 16 + quad * 4 + r) * SEQ;

    int ridx[4][4];
#pragma unroll
    for (int nt = 0; nt < 4; ++nt)
#pragma unroll
      for (int r = 0; r < 4; ++r) ridx[nt][r] = rp[r][nt * 16 + l15];

    __syncthreads();  // drain prologue staging

    const int q_base = qt * 64 + wid * 16 + quad * 4;
    float l_part[4] = {0.f, 0.f, 0.f, 0.f};
    f32x4 o_acc[4] = {};

    for (int kt = 0; kt < qt; ++kt) {
      int cur = kt & 1;
      int ridx2[4][4];
      {
        bf16* Kd = Kb + (cur ^ 1) * 4096;
        bf16* Vd = Vb + (cur ^ 1) * 4096;
#pragma unroll
        for (int it = 0; it < 2; ++it) {
          int c = wid * 2 + it;
          int row = c * 8 + rsub;
          load_lds16(kb0 + (size_t)((kt + 1) * 64 + row) * HDIM + c8 * 8, &Kd[c * 512]);
          load_lds16(vt0 + (size_t)row * SEQ + (kt + 1) * 64 + c8 * 8, &Vd[c * 512]);
        }
#pragma unroll
        for (int nt = 0; nt < 4; ++nt)
#pragma unroll
          for (int r = 0; r < 4; ++r) ridx2[nt][r] = rp[r][(kt + 1) * 64 + nt * 16 + l15];
      }

      const bf16* Ksb = Kb + cur * 4096;
      const bf16* Vtb = Vb + cur * 4096;

      f32x4 sacc[4] = {};
      __builtin_amdgcn_s_setprio(1);
#pragma unroll
      for (int ks = 0; ks < 2; ++ks) {
#pragma unroll
        for (int nt = 0; nt < 4; ++nt) {
          bf16x8 bfr =
              *(const bf16x8*)&Ksb[(nt * 16 + l15) * 64 + ((ks * 4 + quad) ^ (l15 & 7)) * 8];
          sacc[nt] = __builtin_amdgcn_mfma_f32_16x16x32_bf16(aq[ks], bfr, sacc[nt], 0, 0, 0);
        }
      }
      __builtin_amdgcn_s_setprio(0);

#pragma unroll
      for (int nt = 0; nt < 4; ++nt) {
#pragma unroll
        for (int r = 0; r < 4; ++r) {
          float m = __shfl(rv, ridx[nt][r], 64);
          float p = __expf(sacc[nt][r] * m);
          l_part[r] += p;
          int row = prow_w + r;
          int sw = (nt * 2 + (l15 >> 3)) ^ pswz(row);
          Ps[row * 64 + sw * 8 + (l15 & 7)] = __float2bfloat16(p);
        }
      }

      __builtin_amdgcn_s_setprio(1);
#pragma unroll
      for (int ks = 0; ks < 2; ++ks) {
        bf16x8 af = *(const bf16x8*)&Ps[prow_r * 64 + ((ks * 4 + quad) ^ psw_r) * 8];
#pragma unroll
        for (int nt = 0; nt < 4; ++nt) {
          bf16x8 bfr =
              *(const bf16x8*)&Vtb[(nt * 16 + l15) * 64 + ((ks * 4 + quad) ^ (l15 & 7)) * 8];
          o_acc[nt] = __builtin_amdgcn_mfma_f32_16x16x32_bf16(af, bfr, o_acc[nt], 0, 0, 0);
        }
      }
      __builtin_amdgcn_s_setprio(0);

      __syncthreads();

#pragma unroll
      for (int nt = 0; nt < 4; ++nt)
#pragma unroll
        for (int r = 0; r < 4; ++r) ridx[nt][r] = ridx2[nt][r];
    }

    // diagonal tile (causal mask applies here only)
    {
      int cur = qt & 1;
      const bf16* Ksb = Kb + cur * 4096;
      const bf16* Vtb = Vb + cur * 4096;

      f32x4 sacc[4] = {};
      __builtin_amdgcn_s_setprio(1);
#pragma unroll
      for (int ks = 0; ks < 2; ++ks) {
#pragma unroll
        for (int nt = 0; nt < 4; ++nt) {
          bf16x8 bfr =
              *(const bf16x8*)&Ksb[(nt * 16 + l15) * 64 + ((ks * 4 + quad) ^ (l15 & 7)) * 8];
          sacc[nt] = __builtin_amdgcn_mfma_f32_16x16x32_bf16(aq[ks], bfr, sacc[nt], 0, 0, 0);
        }
      }
      __builtin_amdgcn_s_setprio(0);

#pragma unroll
      for (int nt = 0; nt < 4; ++nt) {
#pragma unroll
        for (int r = 0; r < 4; ++r) {
          float m = __shfl(rv, ridx[nt][r], 64);
          float p = __expf(sacc[nt][r] * m);
          int k_abs = qt * 64 + nt * 16 + l15;
          if (k_abs > q_base + r) p = 0.f;
          l_part[r] += p;
          int row = prow_w + r;
          int sw = (nt * 2 + (l15 >> 3)) ^ pswz(row);
          Ps[row * 64 + sw * 8 + (l15 & 7)] = __float2bfloat16(p);
        }
      }

      __builtin_amdgcn_s_setprio(1);
#pragma unroll
      for (int ks = 0; ks < 2; ++ks) {
        bf16x8 af = *(const bf16x8*)&Ps[prow_r * 64 + ((ks * 4 + quad) ^ psw_r) * 8];
#pragma unroll
        for (int nt = 0; nt < 4; ++nt) {
          bf16x8 bfr =
              *(const bf16x8*)&Vtb[(nt * 16 + l15) * 64 + ((ks * 4 + quad) ^ (l15 & 7)) * 8];
          o_acc[nt] = __builtin_amdgcn_mfma_f32_16x16x32_bf16(af, bfr, o_acc[nt], 0, 0, 0);
        }
      }
      __builtin_amdgcn_s_setprio(0);

      __syncthreads();  // all LDS reads done before SufLds aliases K/V dbuf
    }

    // ---- epilogue: reduce l, add masked term, write out + init x2 = x + bo ----
#pragma unroll
    for (int r = 0; r < 4; ++r)
#pragma unroll
      for (int m = 1; m < 16; m <<= 1) l_part[r] += __shfl_xor(l_part[r], m, 64);

    const float* sufb = suf + bh * (size_t)HDIM * SEQ + (size_t)qt * 64;
#pragma unroll
    for (int p = 0; p < 4; ++p) {
      int idx = p * 256 + tid;
      int d = idx >> 4, qq = idx & 15;
      *(float4*)&SufLds[d][qq * 4] = *(const float4*)(sufb + (size_t)d * SEQ + qq * 4);
    }
    __syncthreads();

#pragma unroll
    for (int nt = 0; nt < 4; ++nt) {
      int d = nt * 16 + l15;
#pragma unroll
      for (int r = 0; r < 4; ++r) {
        int row = q_base + r;
        int cnt = (SEQ - 1) - row;  // # masked keys, each contributing exp(0)=1
        float l = l_part[r] + (float)cnt;
        int q_local = wid * 16 + quad * 4 + r;
        float ov = (o_acc[nt][r] + SufLds[d][q_local]) / l;
        size_t oidx = ((size_t)b * SEQ + row) * DIM + h * HDIM + d;
        out[oidx] = __float2bfloat16(ov);
        x2f[oidx] = xin[oidx] + bov[nt];  // pre-init wo's split-K destination
      }
    }
  }
}

// ---------------- launcher ----------------
extern "C" void kernel_launch(void* const* d_in, const int* in_sizes, int n_in,
                              void* d_out, int out_size, void* d_ws, size_t ws_size,
                              hipStream_t stream) {
  const float* x = (const float*)d_in[0];
  const int* rel = (const int*)d_in[1];
  const float* ln1w = (const float*)d_in[2];
  const float* ln1b = (const float*)d_in[3];
  const float* Wqkv = (const float*)d_in[4];
  const float* bqkv = (const float*)d_in[5];
  const float* Wo = (const float*)d_in[6];
  const float* bo = (const float*)d_in[7];
  const float* rel_emb = (const float*)d_in[8];
  const float* ln2w = (const float*)d_in[9];
  const float* ln2b = (const float*)d_in[10];
  const float* Wfc = (const float*)d_in[11];
  const float* bfc = (const float*)d_in[12];
  const float* Wp = (const float*)d_in[13];
  const float* bp = (const float*)d_in[14];
  float* outp = (float*)d_out;  // reference output dtype is float32

  char* ws = (char*)d_ws;
  const size_t MB = 1u << 20;
  // Lifetimes (stream-serial): kb/vb die after attn -> wpT/wfcT reuse them; suf dies after
  // attn; wqkvT dies after qkv; woT dies after wo; x2 lives attn->ln2; fcb (fc->wp, 33.6MB)
  // overlays suf+wqkvT+woT+x2[57..65.6] which are all dead by fc time. Peak ws = 73.8 MB.
  bf16* h = (bf16*)(ws + 0);            // ln1 out -> attn out (dies after wo)
  bf16* qb = (bf16*)(ws + 8 * MB);      // q -> ln2 out
  bf16* kb = (bf16*)(ws + 16 * MB);     // k (dies after attn)
  bf16* wpT = (bf16*)(ws + 16 * MB);    //   -> WpT [1024][4096] bf16 (8MB)
  bf16* vb = (bf16*)(ws + 24 * MB);     // v transposed [B,H,HD,S] (dies after attn)
  bf16* wfcT = (bf16*)(ws + 24 * MB);   //   -> WfcT [4096][1024] bf16 (8MB)
  float* suf = (float*)(ws + 32 * MB);  // V suffix sums (dies after attn)
  bf16* wqkvT = (bf16*)(ws + 49 * MB);  // (6MB, dies after qkv)
  bf16* woT = (bf16*)(ws + 55 * MB);    // (2MB, dies after wo)
  float* x2 = (float*)(ws + 57 * MB);   // residual stream (attn-init -> ln2)
  bf16* fcb = (bf16*)(ws + 32 * MB);    // gelu(fc) [4096][4096] bf16 (33.6MB)

  dim3 tb(32, 8);
  transpose_k<<<dim3(3072 / 32, 1024 / 32), tb, 0, stream>>>(Wqkv, wqkvT, 1024, 3072);
  transpose_k<<<dim3(1024 / 32, 1024 / 32), tb, 0, stream>>>(Wo, woT, 1024, 1024);

  ln_k<<<BATCH * SEQ, 256, 0, stream>>>(x, ln1w, ln1b, h, nullptr, nullptr);

  gemm256_k<<<dim3(3072 / 256, 4096 / 256, 1), 512, 0, stream>>>(
      h, wqkvT, bqkv, 3072, 1024, 1024, 0, qb, kb, vb, nullptr);

  sufv_k<<<BATCH * NH * HDIM, 256, 0, stream>>>(vb, suf);

  // attn: out -> h, and x2 = x + bo (init for wo's split-K atomics)
  attn_k<<<dim3(NH, 16, BATCH), 256, 0, stream>>>(qb, kb, vb, rel, rel_emb, suf, h, x, bo, x2);

  // wo: split-K=4 (klen=256), atomicAdd into pre-initialized x2
  gemm256_k<<<dim3(1024 / 256, 4096 / 256, 4), 512, 0, stream>>>(
      h, woT, nullptr, 1024, 1024, 256, 4, nullptr, nullptr, nullptr, x2);

  transpose_k<<<dim3(4096 / 32, 1024 / 32), tb, 0, stream>>>(Wfc, wfcT, 1024, 4096);
  transpose_k<<<dim3(1024 / 32, 4096 / 32), tb, 0, stream>>>(Wp, wpT, 4096, 1024);

  // ln2: ln out -> qb, and outp = x2 + bp (init for wp's split-K atomics)
  ln_k<<<BATCH * SEQ, 256, 0, stream>>>(x2, ln2w, ln2b, qb, bp, outp);

  gemm256_k<<<dim3(4096 / 256, 4096 / 256, 1), 512, 0, stream>>>(
      qb, wfcT, bfc, 4096, 1024, 1024, 2, fcb, nullptr, nullptr, nullptr);

  // wp: split-K=4 (klen=1024, Kstride=4096), atomicAdd into pre-initialized outp
  gemm256_k<<<dim3(1024 / 256, 4096 / 256, 4), 512, 0, stream>>>(
      fcb, wpT, nullptr, 1024, 4096, 1024, 4, nullptr, nullptr, nullptr, outp);
}

// Round 8
// 434.457 us; speedup vs baseline: 1.1222x; 1.1222x over previous
//
#include <hip/hip_runtime.h>
#include <hip/hip_bf16.h>
#include <math.h>

using bf16 = __hip_bfloat16;
typedef __bf16 bf16x8 __attribute__((ext_vector_type(8)));
typedef float f32x4 __attribute__((ext_vector_type(4)));

#define SEQ 2048
#define DIM 1024
#define NH 16
#define HDIM 64
#define BATCH 2

// async global->LDS, 16B per lane; LDS dest = base + lane*16 (wave-uniform base)
__device__ __forceinline__ void load_lds16(const bf16* g, bf16* l) {
  __builtin_amdgcn_global_load_lds((__attribute__((address_space(1))) void*)g,
                                   (__attribute__((address_space(3))) void*)l, 16, 0, 0);
}

// ---------------- convert+transpose: in f32 [R][C] -> out bf16 [C][R] ----------------
__global__ __launch_bounds__(256) void transpose_k(const float* __restrict__ in,
                                                   bf16* __restrict__ out, int R, int C) {
  __shared__ float tile[32][33];
  int c0 = blockIdx.x * 32, r0 = blockIdx.y * 32;
  int tx = threadIdx.x, ty = threadIdx.y;  // (32,8)
#pragma unroll
  for (int j = 0; j < 4; ++j)
    tile[ty + 8 * j][tx] = in[(size_t)(r0 + ty + 8 * j) * C + c0 + tx];
  __syncthreads();
#pragma unroll
  for (int j = 0; j < 4; ++j)
    out[(size_t)(c0 + ty + 8 * j) * R + r0 + tx] = __float2bfloat16(tile[tx][ty + 8 * j]);
}

// ---------------- layernorm (torch-style: unbiased std, /(std+eps)); f32 in, bf16 out ----
// Optional fused init: initout[row][c] = x[row][c] + addb[c]  (pre-inits a split-K GEMM dest)
__global__ __launch_bounds__(256) void ln_k(const float* __restrict__ x,
                                            const float* __restrict__ w,
                                            const float* __restrict__ bb,
                                            bf16* __restrict__ out,
                                            const float* __restrict__ addb,
                                            float* __restrict__ initout) {
  int row = blockIdx.x, tid = threadIdx.x;
  int wid = tid >> 6, lane = tid & 63;
  const float* xr = x + (size_t)row * DIM;
  float4 vv = *(const float4*)&xr[tid * 4];  // 16B/lane coalesced
  if (initout) {
    float4 ab = *(const float4*)&addb[tid * 4];
    float4 iv;
    iv.x = vv.x + ab.x; iv.y = vv.y + ab.y; iv.z = vv.z + ab.z; iv.w = vv.w + ab.w;
    *(float4*)&initout[(size_t)row * DIM + tid * 4] = iv;
  }
  float v[4] = {vv.x, vv.y, vv.z, vv.w};
  float s = v[0] + v[1] + v[2] + v[3];
#pragma unroll
  for (int m = 1; m < 64; m <<= 1) s += __shfl_xor(s, m, 64);
  __shared__ float red[8];
  if (lane == 0) red[wid] = s;
  __syncthreads();
  float mean = (red[0] + red[1] + red[2] + red[3]) * (1.f / DIM);
  float q = 0.f;
#pragma unroll
  for (int j = 0; j < 4; ++j) {
    v[j] -= mean;
    q += v[j] * v[j];
  }
#pragma unroll
  for (int m = 1; m < 64; m <<= 1) q += __shfl_xor(q, m, 64);
  if (lane == 0) red[4 + wid] = q;
  __syncthreads();
  float ssq = red[4] + red[5] + red[6] + red[7];
  float sd = sqrtf(ssq / (float)(DIM - 1));
  float inv = 1.f / (sd + 1e-5f);
  float4 wv = *(const float4*)&w[tid * 4];
  float4 bv4 = *(const float4*)&bb[tid * 4];
  float wl[4] = {wv.x, wv.y, wv.z, wv.w};
  float bl[4] = {bv4.x, bv4.y, bv4.z, bv4.w};
  unsigned short pk[4];
#pragma unroll
  for (int j = 0; j < 4; ++j)
    pk[j] = __bfloat16_as_ushort(__float2bfloat16(wl[j] * (v[j] * inv) + bl[j]));
  *(uint2*)&out[(size_t)row * DIM + tid * 4] = *(uint2*)pk;
}

// ============ 256x256-tile 8-wave phased GEMM: C[M,N] = A[M,Ks] @ Bt[N,Ks]^T ============
// BK=64 split into two col-halves (ks). 4 phases per K-tile, 2 barriers/phase, counted
// vmcnt(8) only at ph1/ph3. Modes:
//   0: split qkv (q,k -> [B,H,S,HD]; v -> [B,H,HD,S]) + bias
//   2: o0 = gelu(acc + bias)
//   4: split-K partial: atomicAdd(fdst[row*N+col], acc)  (dest pre-initialized, no bias)
// NOTE (r7 lesson): mode 4 only pays when klen is large (deep pipeline amortizes the 4x
// atomic write amplification). wp (klen=1024): 100 vs 115 us. wo (klen=256): 100 vs 29 —
// NEVER split-K a GEMM whose per-split pipeline is <8 k-tiles.
__global__ __launch_bounds__(512) void gemm256_k(
    const bf16* __restrict__ A, const bf16* __restrict__ Bt, const float* __restrict__ bias,
    int N, int Kstride, int klen, int mode, bf16* __restrict__ o0, bf16* __restrict__ o1,
    bf16* __restrict__ o2, float* __restrict__ fdst) {
  __shared__ bf16 LDSb[65536];  // [buf][A ks0|ks1 16KB each][B ks0|ks1] = 128 KB
  int tid = threadIdx.x;
  int wid = tid >> 6, lane = tid & 63, quad = lane >> 4, l15 = lane & 15;
  int wm = wid >> 2, wn = wid & 3;  // 2M x 4N wave grid; per-wave out 128x64
  int m0 = blockIdx.y * 256, n0 = blockIdx.x * 256;
  int grow = lane >> 2;                       // row within 16-row chunk
  int gslot = (lane & 3) ^ ((lane >> 3) & 3); // pre-swizzled global 16B col-slot
  const int nt = klen >> 6;
  const int kOff = blockIdx.z * klen;

  // bias preload BEFORE any staging: oldest vmem, retires first, never perturbs vmcnt counts
  float bv[4] = {0.f, 0.f, 0.f, 0.f};
  if (bias) {
#pragma unroll
    for (int nf = 0; nf < 4; ++nf) bv[nf] = bias[n0 + wn * 64 + nf * 16 + l15];
  }

  auto stageA = [&](int tile, int ks) {
    int bd = tile & 1;
#pragma unroll
    for (int it = 0; it < 2; ++it) {
      int c = wid * 2 + it;  // 16 chunks of 16 rows x 32 cols (1KB) per col-half
      load_lds16(
          A + (size_t)(m0 + c * 16 + grow) * Kstride + kOff + tile * 64 + ks * 32 + gslot * 8,
          &LDSb[bd * 32768 + ks * 8192 + c * 512]);
    }
  };
  auto stageB = [&](int tile, int ks) {
    int bd = tile & 1;
#pragma unroll
    for (int it = 0; it < 2; ++it) {
      int c = wid * 2 + it;
      load_lds16(
          Bt + (size_t)(n0 + c * 16 + grow) * Kstride + kOff + tile * 64 + ks * 32 + gslot * 8,
          &LDSb[bd * 32768 + 16384 + ks * 8192 + c * 512]);
    }
  };

  f32x4 acc[8][4] = {};

  // prologue: tile0 both halves + tile1 ks0; wait oldest batch (tile0 ks0) landed
  stageA(0, 0); stageB(0, 0);
  stageA(0, 1); stageB(0, 1);
  stageA(1, 0); stageB(1, 0);
  asm volatile("s_waitcnt vmcnt(8)" ::: "memory");
  __builtin_amdgcn_sched_barrier(0);
  __builtin_amdgcn_s_barrier();
  __builtin_amdgcn_sched_barrier(0);

#define PHASE(BD, KS, MH, STAGE_STMT, WAIT_STMT)                                             \
  {                                                                                          \
    bf16x8 af[4], bq[4];                                                                     \
    _Pragma("unroll") for (int j = 0; j < 4; ++j) {                                          \
      int r = wm * 128 + (MH) * 64 + j * 16 + l15;                                           \
      af[j] = *(const bf16x8*)&LDSb[(BD) * 32768 + (KS) * 8192 + (r >> 4) * 512 +            \
                                    (r & 15) * 32 + ((quad ^ ((r >> 1) & 3)) << 3)];         \
    }                                                                                        \
    _Pragma("unroll") for (int n = 0; n < 4; ++n) {                                          \
      int r = wn * 64 + n * 16 + l15;                                                        \
      bq[n] = *(const bf16x8*)&LDSb[(BD) * 32768 + 16384 + (KS) * 8192 + (r >> 4) * 512 +    \
                                    (r & 15) * 32 + ((quad ^ ((r >> 1) & 3)) << 3)];         \
    }                                                                                        \
    STAGE_STMT;                                                                              \
    __builtin_amdgcn_sched_barrier(0);                                                       \
    __builtin_amdgcn_s_barrier();                                                            \
    __builtin_amdgcn_sched_barrier(0);                                                       \
    __builtin_amdgcn_s_setprio(1);                                                           \
    _Pragma("unroll") for (int j = 0; j < 4; ++j)                                            \
        _Pragma("unroll") for (int n = 0; n < 4; ++n)                                        \
            acc[(MH) * 4 + j][n] = __builtin_amdgcn_mfma_f32_16x16x32_bf16(                  \
                af[j], bq[n], acc[(MH) * 4 + j][n], 0, 0, 0);                                \
    __builtin_amdgcn_s_setprio(0);                                                           \
    WAIT_STMT;                                                                               \
    __builtin_amdgcn_sched_barrier(0);                                                       \
    __builtin_amdgcn_s_barrier();                                                            \
    __builtin_amdgcn_sched_barrier(0);                                                       \
  }

  for (int t = 0; t < nt; ++t) {
    int bd = t & 1;
    PHASE(bd, 0, 0, { if (t + 1 < nt) stageA(t + 1, 1); }, {});
    PHASE(bd, 0, 1, { if (t + 1 < nt) stageB(t + 1, 1); }, {
      if (t + 1 < nt) asm volatile("s_waitcnt vmcnt(8)" ::: "memory");
      else            asm volatile("s_waitcnt vmcnt(0)" ::: "memory");
    });
    PHASE(bd, 1, 0, { if (t + 2 < nt) stageA(t + 2, 0); }, {});
    PHASE(bd, 1, 1, { if (t + 2 < nt) stageB(t + 2, 0); }, {
      if (t + 2 < nt)      asm volatile("s_waitcnt vmcnt(8)" ::: "memory");
      else if (t + 1 < nt) asm volatile("s_waitcnt vmcnt(4)" ::: "memory");
    });
  }
#undef PHASE

#pragma unroll
  for (int mf = 0; mf < 8; ++mf) {
#pragma unroll
    for (int nf = 0; nf < 4; ++nf) {
      int col = n0 + wn * 64 + nf * 16 + l15;
      int row_base = m0 + wm * 128 + mf * 16 + quad * 4;
      if (mode == 0) {
        int which = col >> 10, d = col & 1023, hh = d >> 6, dd = d & 63;
        int b = row_base >> 11, s2 = row_base & 2047;
        if (which == 2) {
          unsigned short pk[4];
#pragma unroll
          for (int r = 0; r < 4; ++r)
            pk[r] = __bfloat16_as_ushort(__float2bfloat16(acc[mf][nf][r] + bv[nf]));
          *(uint2*)&o2[(((size_t)b * NH + hh) * HDIM + dd) * SEQ + s2] = *(uint2*)pk;
        } else {
          bf16* dst = which == 0 ? o0 : o1;
#pragma unroll
          for (int r = 0; r < 4; ++r)
            dst[(((size_t)b * NH + hh) * SEQ + s2 + r) * HDIM + dd] =
                __float2bfloat16(acc[mf][nf][r] + bv[nf]);
        }
      } else if (mode == 2) {
#pragma unroll
        for (int r = 0; r < 4; ++r) {
          float t2 = acc[mf][nf][r] + bv[nf];
          // gelu via sigmoid: 0.5t(1+tanh(u)) = t*sigmoid(2u)
          float u = 0.7978845608028654f * (t2 + 0.044715f * t2 * t2 * t2);
          float g = t2 / (1.f + __expf(-2.f * u));
          o0[(size_t)(row_base + r) * N + col] = __float2bfloat16(g);
        }
      } else {  // mode 4: split-K partial, dest pre-initialized with residual+bias
#pragma unroll
        for (int r = 0; r < 4; ++r)
          atomicAdd(&fdst[(size_t)(row_base + r) * N + col], acc[mf][nf][r]);
      }
    }
  }
}

// ---------------- GEMM (r2 structure): 64x128 tile, single-buffered ----------------
// mode 1: x2out(f32) = residf(f32) + acc + bias   (used for wo: K=1024, full-machine grid)
template <int TM>
__global__ __launch_bounds__(256) void gemm_k(
    const bf16* __restrict__ A, const bf16* __restrict__ Bt, const float* __restrict__ bias,
    int M, int N, int K, int mode,
    const float* __restrict__ residf, float* __restrict__ x2out, const float* __restrict__ x2in,
    float* __restrict__ outf) {
  constexpr int MT = TM / 32;   // m-fragments per wave
  constexpr int ACH = TM / 8;   // 1KB staging chunks in A tile
  __shared__ bf16 As[TM * 64];
  __shared__ bf16 Bs[128 * 64];
  int tid = threadIdx.x;
  int wid = tid >> 6, lane = tid & 63, quad = lane >> 4, l15 = lane & 15;
  int wm = wid >> 1, wn = wid & 1;
  int m0 = blockIdx.y * TM, n0 = blockIdx.x * 128;
  int rsub = lane >> 3;          // row within an 8-row chunk
  int c8 = (lane & 7) ^ rsub;    // swizzled global column-chunk this lane fetches
  f32x4 acc[MT][4] = {};

  for (int k0 = 0; k0 < K; k0 += 64) {
    __syncthreads();
#pragma unroll
    for (int it = 0; it < ACH / 4; ++it) {
      int c = wid * (ACH / 4) + it;
      int row = c * 8 + rsub;
      load_lds16(A + (size_t)(m0 + row) * K + k0 + c8 * 8, &As[c * 512]);
    }
#pragma unroll
    for (int it = 0; it < 4; ++it) {
      int c = wid * 4 + it;
      int row = c * 8 + rsub;
      load_lds16(Bt + (size_t)(n0 + row) * K + k0 + c8 * 8, &Bs[c * 512]);
    }
    __syncthreads();  // drains vmcnt (global_load_lds) before use
#pragma unroll
    for (int ks = 0; ks < 2; ++ks) {
      bf16x8 af[MT], bfr[4];
#pragma unroll
      for (int mt = 0; mt < MT; ++mt) {
        int r = wm * (MT * 16) + mt * 16 + l15;
        af[mt] = *(const bf16x8*)&As[r * 64 + ((ks * 4 + quad) ^ (r & 7)) * 8];
      }
#pragma unroll
      for (int nt2 = 0; nt2 < 4; ++nt2) {
        int r = wn * 64 + nt2 * 16 + l15;
        bfr[nt2] = *(const bf16x8*)&Bs[r * 64 + ((ks * 4 + quad) ^ (r & 7)) * 8];
      }
#pragma unroll
      for (int mt = 0; mt < MT; ++mt)
#pragma unroll
        for (int nt2 = 0; nt2 < 4; ++nt2)
          acc[mt][nt2] =
              __builtin_amdgcn_mfma_f32_16x16x32_bf16(af[mt], bfr[nt2], acc[mt][nt2], 0, 0, 0);
    }
  }

#pragma unroll
  for (int mt = 0; mt < MT; ++mt) {
#pragma unroll
    for (int nt = 0; nt < 4; ++nt) {
      int col = n0 + wn * 64 + nt * 16 + l15;
      float bvs = bias[col];
      int row_base = m0 + wm * (MT * 16) + mt * 16 + quad * 4;
#pragma unroll
      for (int r = 0; r < 4; ++r) {
        int row = row_base + r;
        float val = acc[mt][nt][r] + bvs;
        size_t i = (size_t)row * N + col;
        if (mode == 1) x2out[i] = residf[i] + val;
        else           outf[i] = x2in[i] + val;
      }
    }
  }
}

// ---------------- V suffix-sum: suf[bh][d][q] = sum_{k>q} Vt[bh][d][k] (fp32) ----------------
__global__ __launch_bounds__(256) void sufv_k(const bf16* __restrict__ vt,
                                              float* __restrict__ suf) {
  int row = blockIdx.x;  // (b*NH+h)*HDIM + d
  const bf16* src = vt + (size_t)row * SEQ;
  float* dst = suf + (size_t)row * SEQ;
  int tid = threadIdx.x;
  float v[8];
  float s = 0.f;
#pragma unroll
  for (int j = 0; j < 8; ++j) {
    v[j] = __bfloat162float(src[tid * 8 + j]);
    s += v[j];
  }
  __shared__ float sc[256];
  sc[tid] = s;
  __syncthreads();
  for (int off = 1; off < 256; off <<= 1) {
    float add = (tid + off < 256) ? sc[tid + off] : 0.f;
    __syncthreads();
    sc[tid] += add;
    __syncthreads();
  }
  float run = (tid < 255) ? sc[tid + 1] : 0.f;  // exclusive suffix carry
#pragma unroll
  for (int j = 7; j >= 0; --j) {
    dst[tid * 8 + j] = run;
    run += v[j];
  }
}

// Ps swizzle: chunk ^ ((row&7) ^ (((row>>3)&1)<<1)) — bijective per row
__device__ __forceinline__ int pswz(int row) { return (row & 7) ^ (((row >> 3) & 1) << 1); }

// ---------------- attention: triangular, fixed-ref softmax, dbuf + swizzled ----------------
// UNIFORM-WORK blocks: two tasks/block (qt=31-y then qt=y, same head) -> uniform per-CU load
// under ANY dispatch mapping. Grid 512 blocks, 2 blocks/CU co-resident.
__global__ __launch_bounds__(256) void attn_k(const bf16* __restrict__ q,
                                              const bf16* __restrict__ k,
                                              const bf16* __restrict__ v,
                                              const int* __restrict__ rel,
                                              const float* __restrict__ rel_emb,
                                              const float* __restrict__ suf,
                                              bf16* __restrict__ out) {
  int h = blockIdx.x;
  int y = blockIdx.y;  // 0..15
  int b = blockIdx.z;
  int tid = threadIdx.x;
  int wid = tid >> 6, lane = tid & 63, quad = lane >> 4, l15 = lane & 15;

  __shared__ __align__(16) char SM[40960];
  bf16* Kb = (bf16*)SM;                        // [2][64][64] swizzled chunks
  bf16* Vb = (bf16*)(SM + 16384);              // [2][64][64] swizzled ([d][key])
  bf16* Ps = (bf16*)(SM + 32768);              // [64][64] swizzled
  float(*SufLds)[68] = (float(*)[68])SM;       // epilogue alias over K/V dbuf (17408 B)

  const size_t bh = (size_t)b * NH + h;
  const bf16* kb0 = k + bh * SEQ * HDIM;
  const bf16* vt0 = v + bh * (size_t)HDIM * SEQ;

  float rv = 0.125f * rel_emb[lane * NH + h];

  int rsub = lane >> 3;
  int c8 = (lane & 7) ^ rsub;  // pre-swizzled source chunk -> linear LDS dest

  const int prow_w = wid * 16 + quad * 4;
  const int prow_r = wid * 16 + l15;
  const int psw_r = pswz(prow_r);

  for (int sub = 0; sub < 2; ++sub) {
    int qt = (sub == 0) ? (31 - y) : y;  // heavy task first; pair sums to uniform work

    const bf16* qb = q + (bh * SEQ + (size_t)qt * 64) * HDIM;
    bf16x8 aq[2];
#pragma unroll
    for (int ks = 0; ks < 2; ++ks)
      aq[ks] = *(const bf16x8*)(qb + (size_t)(wid * 16 + l15) * HDIM + ks * 32 + quad * 8);

    // fence: previous task's epilogue reads of SufLds (aliasing K/V dbuf) must complete
    __syncthreads();

#pragma unroll
    for (int it = 0; it < 2; ++it) {
      int c = wid * 2 + it;
      int row = c * 8 + rsub;
      load_lds16(kb0 + (size_t)row * HDIM + c8 * 8, &Kb[c * 512]);
      load_lds16(vt0 + (size_t)row * SEQ + c8 * 8, &Vb[c * 512]);
    }

    const int* relq = rel + (size_t)b * SEQ * SEQ + (size_t)qt * 64 * SEQ;
    const int* rp[4];
#pragma unroll
    for (int r = 0; r < 4; ++r) rp[r] = relq + (size_t)(wid * 16 + quad * 4 + r) * SEQ;

    int ridx[4][4];
#pragma unroll
    for (int nt = 0; nt < 4; ++nt)
#pragma unroll
      for (int r = 0; r < 4; ++r) ridx[nt][r] = rp[r][nt * 16 + l15];

    __syncthreads();  // drain prologue staging

    const int q_base = qt * 64 + wid * 16 + quad * 4;
    float l_part[4] = {0.f, 0.f, 0.f, 0.f};
    f32x4 o_acc[4] = {};

    for (int kt = 0; kt < qt; ++kt) {
      int cur = kt & 1;
      int ridx2[4][4];
      {
        bf16* Kd = Kb + (cur ^ 1) * 4096;
        bf16* Vd = Vb + (cur ^ 1) * 4096;
#pragma unroll
        for (int it = 0; it < 2; ++it) {
          int c = wid * 2 + it;
          int row = c * 8 + rsub;
          load_lds16(kb0 + (size_t)((kt + 1) * 64 + row) * HDIM + c8 * 8, &Kd[c * 512]);
          load_lds16(vt0 + (size_t)row * SEQ + (kt + 1) * 64 + c8 * 8, &Vd[c * 512]);
        }
#pragma unroll
        for (int nt = 0; nt < 4; ++nt)
#pragma unroll
          for (int r = 0; r < 4; ++r) ridx2[nt][r] = rp[r][(kt + 1) * 64 + nt * 16 + l15];
      }

      const bf16* Ksb = Kb + cur * 4096;
      const bf16* Vtb = Vb + cur * 4096;

      f32x4 sacc[4] = {};
      __builtin_amdgcn_s_setprio(1);
#pragma unroll
      for (int ks = 0; ks < 2; ++ks) {
#pragma unroll
        for (int nt = 0; nt < 4; ++nt) {
          bf16x8 bfr =
              *(const bf16x8*)&Ksb[(nt * 16 + l15) * 64 + ((ks * 4 + quad) ^ (l15 & 7)) * 8];
          sacc[nt] = __builtin_amdgcn_mfma_f32_16x16x32_bf16(aq[ks], bfr, sacc[nt], 0, 0, 0);
        }
      }
      __builtin_amdgcn_s_setprio(0);

#pragma unroll
      for (int nt = 0; nt < 4; ++nt) {
#pragma unroll
        for (int r = 0; r < 4; ++r) {
          float m = __shfl(rv, ridx[nt][r], 64);
          float p = __expf(sacc[nt][r] * m);
          l_part[r] += p;
          int row = prow_w + r;
          int sw = (nt * 2 + (l15 >> 3)) ^ pswz(row);
          Ps[row * 64 + sw * 8 + (l15 & 7)] = __float2bfloat16(p);
        }
      }

      __builtin_amdgcn_s_setprio(1);
#pragma unroll
      for (int ks = 0; ks < 2; ++ks) {
        bf16x8 af = *(const bf16x8*)&Ps[prow_r * 64 + ((ks * 4 + quad) ^ psw_r) * 8];
#pragma unroll
        for (int nt = 0; nt < 4; ++nt) {
          bf16x8 bfr =
              *(const bf16x8*)&Vtb[(nt * 16 + l15) * 64 + ((ks * 4 + quad) ^ (l15 & 7)) * 8];
          o_acc[nt] = __builtin_amdgcn_mfma_f32_16x16x32_bf16(af, bfr, o_acc[nt], 0, 0, 0);
        }
      }
      __builtin_amdgcn_s_setprio(0);

      __syncthreads();

#pragma unroll
      for (int nt = 0; nt < 4; ++nt)
#pragma unroll
        for (int r = 0; r < 4; ++r) ridx[nt][r] = ridx2[nt][r];
    }

    // diagonal tile (causal mask applies here only)
    {
      int cur = qt & 1;
      const bf16* Ksb = Kb + cur * 4096;
      const bf16* Vtb = Vb + cur * 4096;

      f32x4 sacc[4] = {};
      __builtin_amdgcn_s_setprio(1);
#pragma unroll
      for (int ks = 0; ks < 2; ++ks) {
#pragma unroll
        for (int nt = 0; nt < 4; ++nt) {
          bf16x8 bfr =
              *(const bf16x8*)&Ksb[(nt * 16 + l15) * 64 + ((ks * 4 + quad) ^ (l15 & 7)) * 8];
          sacc[nt] = __builtin_amdgcn_mfma_f32_16x16x32_bf16(aq[ks], bfr, sacc[nt], 0, 0, 0);
        }
      }
      __builtin_amdgcn_s_setprio(0);

#pragma unroll
      for (int nt = 0; nt < 4; ++nt) {
#pragma unroll
        for (int r = 0; r < 4; ++r) {
          float m = __shfl(rv, ridx[nt][r], 64);
          float p = __expf(sacc[nt][r] * m);
          int k_abs = qt * 64 + nt * 16 + l15;
          if (k_abs > q_base + r) p = 0.f;
          l_part[r] += p;
          int row = prow_w + r;
          int sw = (nt * 2 + (l15 >> 3)) ^ pswz(row);
          Ps[row * 64 + sw * 8 + (l15 & 7)] = __float2bfloat16(p);
        }
      }

      __builtin_amdgcn_s_setprio(1);
#pragma unroll
      for (int ks = 0; ks < 2; ++ks) {
        bf16x8 af = *(const bf16x8*)&Ps[prow_r * 64 + ((ks * 4 + quad) ^ psw_r) * 8];
#pragma unroll
        for (int nt = 0; nt < 4; ++nt) {
          bf16x8 bfr =
              *(const bf16x8*)&Vtb[(nt * 16 + l15) * 64 + ((ks * 4 + quad) ^ (l15 & 7)) * 8];
          o_acc[nt] = __builtin_amdgcn_mfma_f32_16x16x32_bf16(af, bfr, o_acc[nt], 0, 0, 0);
        }
      }
      __builtin_amdgcn_s_setprio(0);

      __syncthreads();  // all LDS reads done before SufLds aliases K/V dbuf
    }

    // ---- epilogue: reduce l across the 16 lanes holding each row, add masked term ----
#pragma unroll
    for (int r = 0; r < 4; ++r)
#pragma unroll
      for (int m = 1; m < 16; m <<= 1) l_part[r] += __shfl_xor(l_part[r], m, 64);

    const float* sufb = suf + bh * (size_t)HDIM * SEQ + (size_t)qt * 64;
#pragma unroll
    for (int p = 0; p < 4; ++p) {
      int idx = p * 256 + tid;
      int d = idx >> 4, qq = idx & 15;
      *(float4*)&SufLds[d][qq * 4] = *(const float4*)(sufb + (size_t)d * SEQ + qq * 4);
    }
    __syncthreads();

#pragma unroll
    for (int nt = 0; nt < 4; ++nt) {
      int d = nt * 16 + l15;
#pragma unroll
      for (int r = 0; r < 4; ++r) {
        int row = q_base + r;
        int cnt = (SEQ - 1) - row;  // # masked keys, each contributing exp(0)=1
        float l = l_part[r] + (float)cnt;
        int q_local = wid * 16 + quad * 4 + r;
        float ov = (o_acc[nt][r] + SufLds[d][q_local]) / l;
        out[((size_t)b * SEQ + row) * DIM + h * HDIM + d] = __float2bfloat16(ov);
      }
    }
  }
}

// ---------------- launcher ----------------
extern "C" void kernel_launch(void* const* d_in, const int* in_sizes, int n_in,
                              void* d_out, int out_size, void* d_ws, size_t ws_size,
                              hipStream_t stream) {
  const float* x = (const float*)d_in[0];
  const int* rel = (const int*)d_in[1];
  const float* ln1w = (const float*)d_in[2];
  const float* ln1b = (const float*)d_in[3];
  const float* Wqkv = (const float*)d_in[4];
  const float* bqkv = (const float*)d_in[5];
  const float* Wo = (const float*)d_in[6];
  const float* bo = (const float*)d_in[7];
  const float* rel_emb = (const float*)d_in[8];
  const float* ln2w = (const float*)d_in[9];
  const float* ln2b = (const float*)d_in[10];
  const float* Wfc = (const float*)d_in[11];
  const float* bfc = (const float*)d_in[12];
  const float* Wp = (const float*)d_in[13];
  const float* bp = (const float*)d_in[14];
  float* outp = (float*)d_out;  // reference output dtype is float32

  char* ws = (char*)d_ws;
  const size_t MB = 1u << 20;
  // Lifetimes (stream-serial): kb/vb die after attn -> wpT/wfcT reuse them; suf dies after
  // attn; wqkvT dies after qkv; woT dies after wo; x2 lives wo->ln2 (fcb overlay is written
  // by fc AFTER ln2 consumed x2). Peak ws = 73 MB.
  bf16* h = (bf16*)(ws + 0);            // ln1 out -> attn out (dies after wo)
  bf16* qb = (bf16*)(ws + 8 * MB);      // q -> ln2 out
  bf16* kb = (bf16*)(ws + 16 * MB);     // k (dies after attn)
  bf16* wpT = (bf16*)(ws + 16 * MB);    //   -> WpT [1024][4096] bf16 (8MB)
  bf16* vb = (bf16*)(ws + 24 * MB);     // v transposed [B,H,HD,S] (dies after attn)
  bf16* wfcT = (bf16*)(ws + 24 * MB);   //   -> WfcT [4096][1024] bf16 (8MB)
  float* suf = (float*)(ws + 32 * MB);  // V suffix sums (dies after attn)
  bf16* wqkvT = (bf16*)(ws + 49 * MB);  // (6MB, dies after qkv)
  bf16* woT = (bf16*)(ws + 55 * MB);    // (2MB, dies after wo)
  float* x2 = (float*)(ws + 57 * MB);   // residual stream (wo -> ln2)
  bf16* fcb = (bf16*)(ws + 32 * MB);    // gelu(fc) [4096][4096] bf16 (32MB, after ln2)

  dim3 tb(32, 8);
  transpose_k<<<dim3(3072 / 32, 1024 / 32), tb, 0, stream>>>(Wqkv, wqkvT, 1024, 3072);
  transpose_k<<<dim3(1024 / 32, 1024 / 32), tb, 0, stream>>>(Wo, woT, 1024, 1024);

  ln_k<<<BATCH * SEQ, 256, 0, stream>>>(x, ln1w, ln1b, h, nullptr, nullptr);

  gemm256_k<<<dim3(3072 / 256, 4096 / 256, 1), 512, 0, stream>>>(
      h, wqkvT, bqkv, 3072, 1024, 1024, 0, qb, kb, vb, nullptr);

  sufv_k<<<BATCH * NH * HDIM, 256, 0, stream>>>(vb, suf);

  attn_k<<<dim3(NH, 16, BATCH), 256, 0, stream>>>(qb, kb, vb, rel, rel_emb, suf, h);

  // wo: full-machine 64x128 kernel (r7 showed split-K is a disaster at klen=256)
  gemm_k<64><<<dim3(1024 / 128, 4096 / 64), 256, 0, stream>>>(
      h, woT, bo, BATCH * SEQ, 1024, 1024, 1, x, x2, nullptr, nullptr);

  transpose_k<<<dim3(4096 / 32, 1024 / 32), tb, 0, stream>>>(Wfc, wfcT, 1024, 4096);
  transpose_k<<<dim3(1024 / 32, 4096 / 32), tb, 0, stream>>>(Wp, wpT, 4096, 1024);

  // ln2: ln out -> qb, and outp = x2 + bp (init for wp's split-K atomics)
  ln_k<<<BATCH * SEQ, 256, 0, stream>>>(x2, ln2w, ln2b, qb, bp, outp);

  gemm256_k<<<dim3(4096 / 256, 4096 / 256, 1), 512, 0, stream>>>(
      qb, wfcT, bfc, 4096, 1024, 1024, 2, fcb, nullptr, nullptr, nullptr);

  // wp: split-K=4 (klen=1024, Kstride=4096), atomicAdd into pre-initialized outp
  gemm256_k<<<dim3(1024 / 256, 4096 / 256, 4), 512, 0, stream>>>(
      fcb, wpT, nullptr, 1024, 4096, 1024, 4, nullptr, nullptr, nullptr, outp);
}

// Round 10
// 399.859 us; speedup vs baseline: 1.2193x; 1.0865x over previous
//
#include <hip/hip_runtime.h>
#include <hip/hip_bf16.h>
#include <math.h>

using bf16 = __hip_bfloat16;
typedef __bf16 bf16x8 __attribute__((ext_vector_type(8)));
typedef float f32x4 __attribute__((ext_vector_type(4)));

#define SEQ 2048
#define DIM 1024
#define NH 16
#define HDIM 64
#define BATCH 2

// async global->LDS, 16B per lane; LDS dest = base + lane*16 (wave-uniform base)
__device__ __forceinline__ void load_lds16(const bf16* g, bf16* l) {
  __builtin_amdgcn_global_load_lds((__attribute__((address_space(1))) void*)g,
                                   (__attribute__((address_space(3))) void*)l, 16, 0, 0);
}

// ---------------- convert+transpose: in f32 [R][C] -> out bf16 [C][R] ----------------
__global__ __launch_bounds__(256) void transpose_k(const float* __restrict__ in,
                                                   bf16* __restrict__ out, int R, int C) {
  __shared__ float tile[32][33];
  int c0 = blockIdx.x * 32, r0 = blockIdx.y * 32;
  int tx = threadIdx.x, ty = threadIdx.y;  // (32,8)
#pragma unroll
  for (int j = 0; j < 4; ++j)
    tile[ty + 8 * j][tx] = in[(size_t)(r0 + ty + 8 * j) * C + c0 + tx];
  __syncthreads();
#pragma unroll
  for (int j = 0; j < 4; ++j)
    out[(size_t)(c0 + ty + 8 * j) * R + r0 + tx] = __float2bfloat16(tile[tx][ty + 8 * j]);
}

// ---------------- layernorm (torch-style: unbiased std, /(std+eps)); f32 in, bf16 out ----
__global__ __launch_bounds__(256) void ln_k(const float* __restrict__ x,
                                            const float* __restrict__ w,
                                            const float* __restrict__ bb,
                                            bf16* __restrict__ out) {
  int row = blockIdx.x, tid = threadIdx.x;
  int wid = tid >> 6, lane = tid & 63;
  const float* xr = x + (size_t)row * DIM;
  float4 vv = *(const float4*)&xr[tid * 4];  // 16B/lane coalesced
  float v[4] = {vv.x, vv.y, vv.z, vv.w};
  float s = v[0] + v[1] + v[2] + v[3];
#pragma unroll
  for (int m = 1; m < 64; m <<= 1) s += __shfl_xor(s, m, 64);
  __shared__ float red[8];
  if (lane == 0) red[wid] = s;
  __syncthreads();
  float mean = (red[0] + red[1] + red[2] + red[3]) * (1.f / DIM);
  float q = 0.f;
#pragma unroll
  for (int j = 0; j < 4; ++j) {
    v[j] -= mean;
    q += v[j] * v[j];
  }
#pragma unroll
  for (int m = 1; m < 64; m <<= 1) q += __shfl_xor(q, m, 64);
  if (lane == 0) red[4 + wid] = q;
  __syncthreads();
  float ssq = red[4] + red[5] + red[6] + red[7];
  float sd = sqrtf(ssq / (float)(DIM - 1));
  float inv = 1.f / (sd + 1e-5f);
  float4 wv = *(const float4*)&w[tid * 4];
  float4 bv4 = *(const float4*)&bb[tid * 4];
  float wl[4] = {wv.x, wv.y, wv.z, wv.w};
  float bl[4] = {bv4.x, bv4.y, bv4.z, bv4.w};
  unsigned short pk[4];
#pragma unroll
  for (int j = 0; j < 4; ++j)
    pk[j] = __bfloat16_as_ushort(__float2bfloat16(wl[j] * (v[j] * inv) + bl[j]));
  *(uint2*)&out[(size_t)row * DIM + tid * 4] = *(uint2*)pk;
}

// ============ 256x256-tile 8-wave phased GEMM: C[M,N] = A[M,K] @ Bt[N,K]^T + bias ============
// BK=64 split into two col-halves (ks). 4 phases per K-tile, 2 barriers/phase, counted
// vmcnt(8) only at ph1/ph3. B fragments (bq) depend on (wn,KS) only -> read once per KS
// half and PERSISTED across the MH0->MH1 barrier (-8 of 32 ds_read_b128 per K-tile; safe:
// between read and use only the other buffer / other ks region is written, regs immutable).
// mode 0: split qkv (q,k -> [B,H,S,HD]; v -> [B,H,HD,S]).  mode 2: o0 = gelu(acc+bias).
// HISTORY (measured): split-K+atomicAdd variants REGRESS (r7 wo 29->100us, r8 wp ~70->100us;
// 4x f32 atomic write amplification) — do not reintroduce.
__global__ __launch_bounds__(512) void gemm256_k(
    const bf16* __restrict__ A, const bf16* __restrict__ Bt, const float* __restrict__ bias,
    int N, int K, int mode, bf16* __restrict__ o0, bf16* __restrict__ o1,
    bf16* __restrict__ o2) {
  __shared__ bf16 LDSb[65536];  // [buf][A ks0|ks1 16KB each][B ks0|ks1] = 128 KB
  int tid = threadIdx.x;
  int wid = tid >> 6, lane = tid & 63, quad = lane >> 4, l15 = lane & 15;
  int wm = wid >> 2, wn = wid & 3;  // 2M x 4N wave grid; per-wave out 128x64
  int m0 = blockIdx.y * 256, n0 = blockIdx.x * 256;
  int grow = lane >> 2;                       // row within 16-row chunk
  int gslot = (lane & 3) ^ ((lane >> 3) & 3); // pre-swizzled global 16B col-slot
  const int nt = K >> 6;

  // bias preload BEFORE any staging: oldest vmem, retires first, never perturbs vmcnt counts
  float bv[4];
#pragma unroll
  for (int nf = 0; nf < 4; ++nf) bv[nf] = bias[n0 + wn * 64 + nf * 16 + l15];

  auto stageA = [&](int tile, int ks) {
    int bd = tile & 1;
#pragma unroll
    for (int it = 0; it < 2; ++it) {
      int c = wid * 2 + it;  // 16 chunks of 16 rows x 32 cols (1KB) per col-half
      load_lds16(A + (size_t)(m0 + c * 16 + grow) * K + tile * 64 + ks * 32 + gslot * 8,
                 &LDSb[bd * 32768 + ks * 8192 + c * 512]);
    }
  };
  auto stageB = [&](int tile, int ks) {
    int bd = tile & 1;
#pragma unroll
    for (int it = 0; it < 2; ++it) {
      int c = wid * 2 + it;
      load_lds16(Bt + (size_t)(n0 + c * 16 + grow) * K + tile * 64 + ks * 32 + gslot * 8,
                 &LDSb[bd * 32768 + 16384 + ks * 8192 + c * 512]);
    }
  };

  f32x4 acc[8][4] = {};
  bf16x8 bq[4];  // persists across MH0->MH1 (registers; LDS overwrite cannot touch it)

  // prologue: tile0 both halves + tile1 ks0; wait oldest batch (tile0 ks0) landed
  stageA(0, 0); stageB(0, 0);
  stageA(0, 1); stageB(0, 1);
  stageA(1, 0); stageB(1, 0);
  asm volatile("s_waitcnt vmcnt(8)" ::: "memory");
  __builtin_amdgcn_sched_barrier(0);
  __builtin_amdgcn_s_barrier();
  __builtin_amdgcn_sched_barrier(0);

#define PHASE(BD, KS, MH, LOADB, STAGE_STMT, WAIT_STMT)                                      \
  {                                                                                          \
    bf16x8 af[4];                                                                            \
    _Pragma("unroll") for (int j = 0; j < 4; ++j) {                                          \
      int r = wm * 128 + (MH) * 64 + j * 16 + l15;                                           \
      af[j] = *(const bf16x8*)&LDSb[(BD) * 32768 + (KS) * 8192 + (r >> 4) * 512 +            \
                                    (r & 15) * 32 + ((quad ^ ((r >> 1) & 3)) << 3)];         \
    }                                                                                        \
    if (LOADB) {                                                                             \
      _Pragma("unroll") for (int n = 0; n < 4; ++n) {                                        \
        int r = wn * 64 + n * 16 + l15;                                                      \
        bq[n] = *(const bf16x8*)&LDSb[(BD) * 32768 + 16384 + (KS) * 8192 + (r >> 4) * 512 +  \
                                      (r & 15) * 32 + ((quad ^ ((r >> 1) & 3)) << 3)];       \
      }                                                                                      \
    }                                                                                        \
    STAGE_STMT;                                                                              \
    __builtin_amdgcn_sched_barrier(0);                                                       \
    __builtin_amdgcn_s_barrier();                                                            \
    __builtin_amdgcn_sched_barrier(0);                                                       \
    __builtin_amdgcn_s_setprio(1);                                                           \
    _Pragma("unroll") for (int j = 0; j < 4; ++j)                                            \
        _Pragma("unroll") for (int n = 0; n < 4; ++n)                                        \
            acc[(MH) * 4 + j][n] = __builtin_amdgcn_mfma_f32_16x16x32_bf16(                  \
                af[j], bq[n], acc[(MH) * 4 + j][n], 0, 0, 0);                                \
    __builtin_amdgcn_s_setprio(0);                                                           \
    WAIT_STMT;                                                                               \
    __builtin_amdgcn_sched_barrier(0);                                                       \
    __builtin_amdgcn_s_barrier();                                                            \
    __builtin_amdgcn_sched_barrier(0);                                                       \
  }

  for (int t = 0; t < nt; ++t) {
    int bd = t & 1;
    PHASE(bd, 0, 0, 1, { if (t + 1 < nt) stageA(t + 1, 1); }, {});
    PHASE(bd, 0, 1, 0, { if (t + 1 < nt) stageB(t + 1, 1); }, {
      if (t + 1 < nt) asm volatile("s_waitcnt vmcnt(8)" ::: "memory");
      else            asm volatile("s_waitcnt vmcnt(0)" ::: "memory");
    });
    PHASE(bd, 1, 0, 1, { if (t + 2 < nt) stageA(t + 2, 0); }, {});
    PHASE(bd, 1, 1, 0, { if (t + 2 < nt) stageB(t + 2, 0); }, {
      if (t + 2 < nt)      asm volatile("s_waitcnt vmcnt(8)" ::: "memory");
      else if (t + 1 < nt) asm volatile("s_waitcnt vmcnt(4)" ::: "memory");
    });
  }
#undef PHASE

#pragma unroll
  for (int mf = 0; mf < 8; ++mf) {
#pragma unroll
    for (int nf = 0; nf < 4; ++nf) {
      int col = n0 + wn * 64 + nf * 16 + l15;
      int row_base = m0 + wm * 128 + mf * 16 + quad * 4;
      if (mode == 0) {
        int which = col >> 10, d = col & 1023, hh = d >> 6, dd = d & 63;
        int b = row_base >> 11, s2 = row_base & 2047;
        if (which == 2) {
          unsigned short pk[4];
#pragma unroll
          for (int r = 0; r < 4; ++r)
            pk[r] = __bfloat16_as_ushort(__float2bfloat16(acc[mf][nf][r] + bv[nf]));
          *(uint2*)&o2[(((size_t)b * NH + hh) * HDIM + dd) * SEQ + s2] = *(uint2*)pk;
        } else {
          bf16* dst = which == 0 ? o0 : o1;
#pragma unroll
          for (int r = 0; r < 4; ++r)
            dst[(((size_t)b * NH + hh) * SEQ + s2 + r) * HDIM + dd] =
                __float2bfloat16(acc[mf][nf][r] + bv[nf]);
        }
      } else {
#pragma unroll
        for (int r = 0; r < 4; ++r) {
          float t2 = acc[mf][nf][r] + bv[nf];
          // gelu via sigmoid: 0.5t(1+tanh(u)) = t*sigmoid(2u)
          float u = 0.7978845608028654f * (t2 + 0.044715f * t2 * t2 * t2);
          float g = t2 / (1.f + __expf(-2.f * u));
          o0[(size_t)(row_base + r) * N + col] = __float2bfloat16(g);
        }
      }
    }
  }
}

// ---------------- GEMM (r2 structure): 64x128 tile, single-buffered ----------------
// mode 1: x2out(f32) = residf(f32) + acc + bias   (wo)
// mode 3: outf(f32) = x2in(f32) + acc + bias      (wp)
template <int TM>
__global__ __launch_bounds__(256) void gemm_k(
    const bf16* __restrict__ A, const bf16* __restrict__ Bt, const float* __restrict__ bias,
    int M, int N, int K, int mode,
    const float* __restrict__ residf, float* __restrict__ x2out, const float* __restrict__ x2in,
    float* __restrict__ outf) {
  constexpr int MT = TM / 32;   // m-fragments per wave
  constexpr int ACH = TM / 8;   // 1KB staging chunks in A tile
  __shared__ bf16 As[TM * 64];
  __shared__ bf16 Bs[128 * 64];
  int tid = threadIdx.x;
  int wid = tid >> 6, lane = tid & 63, quad = lane >> 4, l15 = lane & 15;
  int wm = wid >> 1, wn = wid & 1;
  int m0 = blockIdx.y * TM, n0 = blockIdx.x * 128;
  int rsub = lane >> 3;          // row within an 8-row chunk
  int c8 = (lane & 7) ^ rsub;    // swizzled global column-chunk this lane fetches
  f32x4 acc[MT][4] = {};

  for (int k0 = 0; k0 < K; k0 += 64) {
    __syncthreads();
#pragma unroll
    for (int it = 0; it < ACH / 4; ++it) {
      int c = wid * (ACH / 4) + it;
      int row = c * 8 + rsub;
      load_lds16(A + (size_t)(m0 + row) * K + k0 + c8 * 8, &As[c * 512]);
    }
#pragma unroll
    for (int it = 0; it < 4; ++it) {
      int c = wid * 4 + it;
      int row = c * 8 + rsub;
      load_lds16(Bt + (size_t)(n0 + row) * K + k0 + c8 * 8, &Bs[c * 512]);
    }
    __syncthreads();  // drains vmcnt (global_load_lds) before use
#pragma unroll
    for (int ks = 0; ks < 2; ++ks) {
      bf16x8 af[MT], bfr[4];
#pragma unroll
      for (int mt = 0; mt < MT; ++mt) {
        int r = wm * (MT * 16) + mt * 16 + l15;
        af[mt] = *(const bf16x8*)&As[r * 64 + ((ks * 4 + quad) ^ (r & 7)) * 8];
      }
#pragma unroll
      for (int nt2 = 0; nt2 < 4; ++nt2) {
        int r = wn * 64 + nt2 * 16 + l15;
        bfr[nt2] = *(const bf16x8*)&Bs[r * 64 + ((ks * 4 + quad) ^ (r & 7)) * 8];
      }
#pragma unroll
      for (int mt = 0; mt < MT; ++mt)
#pragma unroll
        for (int nt2 = 0; nt2 < 4; ++nt2)
          acc[mt][nt2] =
              __builtin_amdgcn_mfma_f32_16x16x32_bf16(af[mt], bfr[nt2], acc[mt][nt2], 0, 0, 0);
    }
  }

#pragma unroll
  for (int mt = 0; mt < MT; ++mt) {
#pragma unroll
    for (int nt = 0; nt < 4; ++nt) {
      int col = n0 + wn * 64 + nt * 16 + l15;
      float bvs = bias[col];
      int row_base = m0 + wm * (MT * 16) + mt * 16 + quad * 4;
#pragma unroll
      for (int r = 0; r < 4; ++r) {
        int row = row_base + r;
        float val = acc[mt][nt][r] + bvs;
        size_t i = (size_t)row * N + col;
        if (mode == 1) x2out[i] = residf[i] + val;
        else           outf[i] = x2in[i] + val;
      }
    }
  }
}

// ---------------- V suffix-sum: suf[bh][d][q] = sum_{k>q} Vt[bh][d][k] (fp32) ----------------
__global__ __launch_bounds__(256) void sufv_k(const bf16* __restrict__ vt,
                                              float* __restrict__ suf) {
  int row = blockIdx.x;  // (b*NH+h)*HDIM + d
  const bf16* src = vt + (size_t)row * SEQ;
  float* dst = suf + (size_t)row * SEQ;
  int tid = threadIdx.x;
  float v[8];
  float s = 0.f;
#pragma unroll
  for (int j = 0; j < 8; ++j) {
    v[j] = __bfloat162float(src[tid * 8 + j]);
    s += v[j];
  }
  __shared__ float sc[256];
  sc[tid] = s;
  __syncthreads();
  for (int off = 1; off < 256; off <<= 1) {
    float add = (tid + off < 256) ? sc[tid + off] : 0.f;
    __syncthreads();
    sc[tid] += add;
    __syncthreads();
  }
  float run = (tid < 255) ? sc[tid + 1] : 0.f;  // exclusive suffix carry
#pragma unroll
  for (int j = 7; j >= 0; --j) {
    dst[tid * 8 + j] = run;
    run += v[j];
  }
}

// Ps swizzle: chunk ^ ((row&7) ^ (((row>>3)&1)<<1)) — bijective per row
__device__ __forceinline__ int pswz(int row) { return (row & 7) ^ (((row >> 3) & 1) << 1); }

// ---------------- attention: triangular, fixed-ref softmax, dbuf + swizzled, 4 blocks/CU ----
// r4 configuration (measured best 73.4us): one qt task per block, heavy blocks first,
// grid 1024 = 4 blocks/CU co-resident. (r5 static-balance and r6 pairing both measured
// worse: 84.3 / 77.5 — dispatch-mapping guesses fail; imbalanced-but-deep wins.)
__global__ __launch_bounds__(256) void attn_k(const bf16* __restrict__ q,
                                              const bf16* __restrict__ k,
                                              const bf16* __restrict__ v,
                                              const int* __restrict__ rel,
                                              const float* __restrict__ rel_emb,
                                              const float* __restrict__ suf,
                                              bf16* __restrict__ out) {
  int h = blockIdx.x;
  int qt = (SEQ / 64 - 1) - blockIdx.y;  // heavy blocks first
  int b = blockIdx.z;
  int tid = threadIdx.x;
  int wid = tid >> 6, lane = tid & 63, quad = lane >> 4, l15 = lane & 15;

  __shared__ __align__(16) char SM[40960];
  bf16* Kb = (bf16*)SM;                        // [2][64][64] swizzled chunks
  bf16* Vb = (bf16*)(SM + 16384);              // [2][64][64] swizzled ([d][key])
  bf16* Ps = (bf16*)(SM + 32768);              // [64][64] swizzled
  float(*SufLds)[68] = (float(*)[68])SM;       // epilogue alias over K/V dbuf (17408 B)

  const size_t bh = (size_t)b * NH + h;
  const bf16* qb = q + (bh * SEQ + (size_t)qt * 64) * HDIM;
  const bf16* kb0 = k + bh * SEQ * HDIM;
  const bf16* vt0 = v + bh * (size_t)HDIM * SEQ;

  float rv = 0.125f * rel_emb[lane * NH + h];

  int rsub = lane >> 3;
  int c8 = (lane & 7) ^ rsub;  // pre-swizzled source chunk -> linear LDS dest

  bf16x8 aq[2];
#pragma unroll
  for (int ks = 0; ks < 2; ++ks)
    aq[ks] = *(const bf16x8*)(qb + (size_t)(wid * 16 + l15) * HDIM + ks * 32 + quad * 8);

#pragma unroll
  for (int it = 0; it < 2; ++it) {
    int c = wid * 2 + it;
    int row = c * 8 + rsub;
    load_lds16(kb0 + (size_t)row * HDIM + c8 * 8, &Kb[c * 512]);
    load_lds16(vt0 + (size_t)row * SEQ + c8 * 8, &Vb[c * 512]);
  }

  const int* relq = rel + (size_t)b * SEQ * SEQ + (size_t)qt * 64 * SEQ;
  const int* rp[4];
#pragma unroll
  for (int r = 0; r < 4; ++r) rp[r] = relq + (size_t)(wid * 16 + quad * 4 + r) * SEQ;

  int ridx[4][4];
#pragma unroll
  for (int nt = 0; nt < 4; ++nt)
#pragma unroll
    for (int r = 0; r < 4; ++r) ridx[nt][r] = rp[r][nt * 16 + l15];

  __syncthreads();  // drain prologue staging

  const int q_base = qt * 64 + wid * 16 + quad * 4;
  const int prow_w = wid * 16 + quad * 4;
  const int prow_r = wid * 16 + l15;
  const int psw_r = pswz(prow_r);
  float l_part[4] = {0.f, 0.f, 0.f, 0.f};
  f32x4 o_acc[4] = {};

  for (int kt = 0; kt < qt; ++kt) {
    int cur = kt & 1;
    int ridx2[4][4];
    {
      bf16* Kd = Kb + (cur ^ 1) * 4096;
      bf16* Vd = Vb + (cur ^ 1) * 4096;
#pragma unroll
      for (int it = 0; it < 2; ++it) {
        int c = wid * 2 + it;
        int row = c * 8 + rsub;
        load_lds16(kb0 + (size_t)((kt + 1) * 64 + row) * HDIM + c8 * 8, &Kd[c * 512]);
        load_lds16(vt0 + (size_t)row * SEQ + (kt + 1) * 64 + c8 * 8, &Vd[c * 512]);
      }
#pragma unroll
      for (int nt = 0; nt < 4; ++nt)
#pragma unroll
        for (int r = 0; r < 4; ++r) ridx2[nt][r] = rp[r][(kt + 1) * 64 + nt * 16 + l15];
    }

    const bf16* Ksb = Kb + cur * 4096;
    const bf16* Vtb = Vb + cur * 4096;

    f32x4 sacc[4] = {};
    __builtin_amdgcn_s_setprio(1);
#pragma unroll
    for (int ks = 0; ks < 2; ++ks) {
#pragma unroll
      for (int nt = 0; nt < 4; ++nt) {
        bf16x8 bfr = *(const bf16x8*)&Ksb[(nt * 16 + l15) * 64 + ((ks * 4 + quad) ^ (l15 & 7)) * 8];
        sacc[nt] = __builtin_amdgcn_mfma_f32_16x16x32_bf16(aq[ks], bfr, sacc[nt], 0, 0, 0);
      }
    }
    __builtin_amdgcn_s_setprio(0);

#pragma unroll
    for (int nt = 0; nt < 4; ++nt) {
#pragma unroll
      for (int r = 0; r < 4; ++r) {
        float m = __shfl(rv, ridx[nt][r], 64);
        float p = __expf(sacc[nt][r] * m);
        l_part[r] += p;
        int row = prow_w + r;
        int sw = (nt * 2 + (l15 >> 3)) ^ pswz(row);
        Ps[row * 64 + sw * 8 + (l15 & 7)] = __float2bfloat16(p);
      }
    }

    __builtin_amdgcn_s_setprio(1);
#pragma unroll
    for (int ks = 0; ks < 2; ++ks) {
      bf16x8 af = *(const bf16x8*)&Ps[prow_r * 64 + ((ks * 4 + quad) ^ psw_r) * 8];
#pragma unroll
      for (int nt = 0; nt < 4; ++nt) {
        bf16x8 bfr = *(const bf16x8*)&Vtb[(nt * 16 + l15) * 64 + ((ks * 4 + quad) ^ (l15 & 7)) * 8];
        o_acc[nt] = __builtin_amdgcn_mfma_f32_16x16x32_bf16(af, bfr, o_acc[nt], 0, 0, 0);
      }
    }
    __builtin_amdgcn_s_setprio(0);

    __syncthreads();

#pragma unroll
    for (int nt = 0; nt < 4; ++nt)
#pragma unroll
      for (int r = 0; r < 4; ++r) ridx[nt][r] = ridx2[nt][r];
  }

  // diagonal tile (causal mask applies here only)
  {
    int cur = qt & 1;
    const bf16* Ksb = Kb + cur * 4096;
    const bf16* Vtb = Vb + cur * 4096;

    f32x4 sacc[4] = {};
    __builtin_amdgcn_s_setprio(1);
#pragma unroll
    for (int ks = 0; ks < 2; ++ks) {
#pragma unroll
      for (int nt = 0; nt < 4; ++nt) {
        bf16x8 bfr = *(const bf16x8*)&Ksb[(nt * 16 + l15) * 64 + ((ks * 4 + quad) ^ (l15 & 7)) * 8];
        sacc[nt] = __builtin_amdgcn_mfma_f32_16x16x32_bf16(aq[ks], bfr, sacc[nt], 0, 0, 0);
      }
    }
    __builtin_amdgcn_s_setprio(0);

#pragma unroll
    for (int nt = 0; nt < 4; ++nt) {
#pragma unroll
      for (int r = 0; r < 4; ++r) {
        float m = __shfl(rv, ridx[nt][r], 64);
        float p = __expf(sacc[nt][r] * m);
        int k_abs = qt * 64 + nt * 16 + l15;
        if (k_abs > q_base + r) p = 0.f;
        l_part[r] += p;
        int row = prow_w + r;
        int sw = (nt * 2 + (l15 >> 3)) ^ pswz(row);
        Ps[row * 64 + sw * 8 + (l15 & 7)] = __float2bfloat16(p);
      }
    }

    __builtin_amdgcn_s_setprio(1);
#pragma unroll
    for (int ks = 0; ks < 2; ++ks) {
      bf16x8 af = *(const bf16x8*)&Ps[prow_r * 64 + ((ks * 4 + quad) ^ psw_r) * 8];
#pragma unroll
      for (int nt = 0; nt < 4; ++nt) {
        bf16x8 bfr = *(const bf16x8*)&Vtb[(nt * 16 + l15) * 64 + ((ks * 4 + quad) ^ (l15 & 7)) * 8];
        o_acc[nt] = __builtin_amdgcn_mfma_f32_16x16x32_bf16(af, bfr, o_acc[nt], 0, 0, 0);
      }
    }
    __builtin_amdgcn_s_setprio(0);

    __syncthreads();  // all LDS reads done before SufLds aliases K/V dbuf
  }

#pragma unroll
  for (int r = 0; r < 4; ++r)
#pragma unroll
    for (int m = 1; m < 16; m <<= 1) l_part[r] += __shfl_xor(l_part[r], m, 64);

  const float* sufb = suf + bh * (size_t)HDIM * SEQ + (size_t)qt * 64;
#pragma unroll
  for (int p = 0; p < 4; ++p) {
    int idx = p * 256 + tid;
    int d = idx >> 4, qq = idx & 15;
    *(float4*)&SufLds[d][qq * 4] = *(const float4*)(sufb + (size_t)d * SEQ + qq * 4);
  }
  __syncthreads();

#pragma unroll
  for (int nt = 0; nt < 4; ++nt) {
    int d = nt * 16 + l15;
#pragma unroll
    for (int r = 0; r < 4; ++r) {
      int row = q_base + r;
      int cnt = (SEQ - 1) - row;  // # masked keys, each contributing exp(0)=1
      float l = l_part[r] + (float)cnt;
      int q_local = wid * 16 + quad * 4 + r;
      float ov = (o_acc[nt][r] + SufLds[d][q_local]) / l;
      out[((size_t)b * SEQ + row) * DIM + h * HDIM + d] = __float2bfloat16(ov);
    }
  }
}

// ---------------- launcher ----------------
extern "C" void kernel_launch(void* const* d_in, const int* in_sizes, int n_in,
                              void* d_out, int out_size, void* d_ws, size_t ws_size,
                              hipStream_t stream) {
  const float* x = (const float*)d_in[0];
  const int* rel = (const int*)d_in[1];
  const float* ln1w = (const float*)d_in[2];
  const float* ln1b = (const float*)d_in[3];
  const float* Wqkv = (const float*)d_in[4];
  const float* bqkv = (const float*)d_in[5];
  const float* Wo = (const float*)d_in[6];
  const float* bo = (const float*)d_in[7];
  const float* rel_emb = (const float*)d_in[8];
  const float* ln2w = (const float*)d_in[9];
  const float* ln2b = (const float*)d_in[10];
  const float* Wfc = (const float*)d_in[11];
  const float* bfc = (const float*)d_in[12];
  const float* Wp = (const float*)d_in[13];
  const float* bp = (const float*)d_in[14];
  float* outp = (float*)d_out;  // reference output dtype is float32

  char* ws = (char*)d_ws;
  const size_t MB = 1u << 20;
  // PROVEN r0-r6 lifetime layout (r9 failed by overlaying fcb on live x2 — fc writes fcb
  // BEFORE wp reads x2, so fcb must not intersect x2):
  //   x2/suf SHARE 32..48MB (suf dies at attn; x2 born at wo, read by wp at the end)
  //   fcb 48..80MB overlays wqkvT(48..54, dead after qkv) + woT(54..56, dead after wo)
  //   wfcT/wpT overlay kb/vb (dead after attn)
  bf16* h = (bf16*)(ws + 0);           // ln1 out -> attn out
  bf16* qb = (bf16*)(ws + 8 * MB);     // q -> ln2 out
  bf16* kb = (bf16*)(ws + 16 * MB);    // k -> wfcT
  bf16* vb = (bf16*)(ws + 24 * MB);    // v transposed [B,H,HD,S] -> wpT
  float* x2 = (float*)(ws + 32 * MB);  // early: V suffix-sums; later: residual stream
  float* suf = (float*)(ws + 32 * MB);
  bf16* fcb = (bf16*)(ws + 48 * MB);   // gelu(fc); early: wqkvT@48, woT@54
  bf16* wqkvT = (bf16*)(ws + 48 * MB);
  bf16* woT = (bf16*)(ws + 54 * MB);
  bf16* wfcT = (bf16*)(ws + 16 * MB);
  bf16* wpT = (bf16*)(ws + 24 * MB);

  dim3 tb(32, 8);
  transpose_k<<<dim3(3072 / 32, 1024 / 32), tb, 0, stream>>>(Wqkv, wqkvT, 1024, 3072);
  transpose_k<<<dim3(1024 / 32, 1024 / 32), tb, 0, stream>>>(Wo, woT, 1024, 1024);

  ln_k<<<BATCH * SEQ, 256, 0, stream>>>(x, ln1w, ln1b, h);

  gemm256_k<<<dim3(3072 / 256, 4096 / 256), 512, 0, stream>>>(
      h, wqkvT, bqkv, 3072, 1024, 0, qb, kb, vb);

  sufv_k<<<BATCH * NH * HDIM, 256, 0, stream>>>(vb, suf);

  attn_k<<<dim3(NH, SEQ / 64, BATCH), 256, 0, stream>>>(qb, kb, vb, rel, rel_emb, suf, h);

  gemm_k<64><<<dim3(1024 / 128, 4096 / 64), 256, 0, stream>>>(
      h, woT, bo, BATCH * SEQ, 1024, 1024, 1, x, x2, nullptr, nullptr);

  transpose_k<<<dim3(4096 / 32, 1024 / 32), tb, 0, stream>>>(Wfc, wfcT, 1024, 4096);
  transpose_k<<<dim3(1024 / 32, 4096 / 32), tb, 0, stream>>>(Wp, wpT, 4096, 1024);

  ln_k<<<BATCH * SEQ, 256, 0, stream>>>(x2, ln2w, ln2b, qb);

  gemm256_k<<<dim3(4096 / 256, 4096 / 256), 512, 0, stream>>>(
      qb, wfcT, bfc, 4096, 1024, 2, fcb, nullptr, nullptr);

  gemm_k<64><<<dim3(1024 / 128, 4096 / 64), 256, 0, stream>>>(
      fcb, wpT, bp, BATCH * SEQ, 1024, 4096, 3, nullptr, nullptr, x2, outp);
}